// Round 9
// baseline (249.442 us; speedup 1.0000x reference)
//
#include <hip/hip_runtime.h>
#include <hip/hip_bf16.h>
#include <math.h>
#include <stdint.h>

typedef short bf16x8 __attribute__((ext_vector_type(8)));
typedef float f32x4 __attribute__((ext_vector_type(4)));
typedef float f32x16 __attribute__((ext_vector_type(16)));

#define NROW 4096
#define NEGN 4088
#define KCLS 8
#define HHALF 8372224u

// ---------------------------------------------------------------------------
// Threefry2x32 (JAX-compatible) and gumbel mapping (validated rounds 0-8)
// ---------------------------------------------------------------------------
__device__ __forceinline__ uint32_t rotl32(uint32_t v, int r) {
    return (v << r) | (v >> (32 - r));
}

__device__ __forceinline__ void threefry2x32(uint32_t k0, uint32_t k1,
                                             uint32_t& x0, uint32_t& x1) {
    uint32_t ks[3] = {k0, k1, k0 ^ k1 ^ 0x1BD11BDAu};
    const int rot[2][4] = {{13, 15, 26, 6}, {17, 29, 16, 24}};
    x0 += ks[0];
    x1 += ks[1];
#pragma unroll
    for (int i = 0; i < 5; ++i) {
#pragma unroll
        for (int r = 0; r < 4; ++r) {
            x0 += x1;
            x1 = rotl32(x1, rot[i & 1][r]);
            x1 ^= x0;
        }
        x0 += ks[(i + 1) % 3];
        x1 += ks[(i + 2) % 3] + (uint32_t)(i + 1);
    }
}

__device__ __forceinline__ float gumbel_from_bits(uint32_t bits) {
    uint32_t fb = (bits >> 9) | 0x3f800000u;
    float u = __uint_as_float(fb) - 1.0f;
    const float tiny = 1.1754943508222875e-38f;
    u = u * (1.0f - tiny) + tiny;
    u = fmaxf(tiny, u);
    return -logf(-logf(u));
}

__device__ __forceinline__ float softplus_f(float x) {
    return fmaxf(x, 0.0f) + log1pf(expf(-fabsf(x)));
}

// ---------------------------------------------------------------------------
// Cross-lane XOR exchange with cheapest available lowering (validated r7)
// ---------------------------------------------------------------------------
template <int M>
__device__ __forceinline__ int lxori(int i) {
    if constexpr (M == 1 || M == 2 || M == 3 || M == 7 || M == 8 || M == 15) {
        constexpr int ctrl = (M == 1) ? 0xB1
                           : (M == 2) ? 0x4E
                           : (M == 3) ? 0x1B
                           : (M == 7) ? 0x141
                           : (M == 8) ? 0x128
                                      : 0x140;
        return __builtin_amdgcn_update_dpp(i, i, ctrl, 0xf, 0xf, false);
    } else if constexpr (M == 4 || M == 16) {
        constexpr int off = (M == 4) ? 0x101F : 0x401F;
        return __builtin_amdgcn_ds_swizzle(i, off);
    } else if constexpr (M == 31) {
        return lxori<16>(lxori<15>(i));
    } else {
        return __shfl_xor(i, M, 64);
    }
}

template <int M>
__device__ __forceinline__ float lxorf(float x) {
    return __int_as_float(lxori<M>(__float_as_int(x)));
}

// ---------------------------------------------------------------------------
// f32 -> bf16 hi/lo split (validated round 4)
// ---------------------------------------------------------------------------
__global__ __launch_bounds__(256) void convert_kernel(const float* __restrict__ X,
                                                      ushort* __restrict__ Xhi,
                                                      ushort* __restrict__ Xlo,
                                                      int total4) {
    int i = blockIdx.x * 256 + threadIdx.x;
    if (i >= total4) return;
    float4 x = ((const float4*)X)[i];
    float xs[4] = {x.x, x.y, x.z, x.w};
    ushort h[4], l[4];
#pragma unroll
    for (int j = 0; j < 4; ++j) {
        __hip_bfloat16 hb = __float2bfloat16(xs[j]);
        float hf = __bfloat162float(hb);
        __hip_bfloat16 lb = __float2bfloat16(xs[j] - hf);
        h[j] = *(ushort*)&hb;
        l[j] = *(ushort*)&lb;
    }
    ((ushort4*)Xhi)[i] = make_ushort4(h[0], h[1], h[2], h[3]);
    ((ushort4*)Xlo)[i] = make_ushort4(l[0], l[1], l[2], l[3]);
}

// ---------------------------------------------------------------------------
// MFMA GEMM, TRIANGULAR, 32x32x16 shape: only lower-triangle tiles (i >= j);
// off-diagonal tiles mirror into the upper triangle via float4 stores.
// sim = Hi*Hi^T + Hi*Lo^T + Lo*Hi^T.
// C/D layout (m74/m101): col = lane&31, row = (reg&3) + 8*(reg>>2) + 4*(lane>>5)
// ---------------------------------------------------------------------------
__device__ __forceinline__ void gload_lds16(const void* g, void* l) {
    __builtin_amdgcn_global_load_lds((const __attribute__((address_space(1))) void*)g,
                                     (__attribute__((address_space(3))) void*)l, 16, 0, 0);
}

__global__ __launch_bounds__(256) void gemm_mfma(const ushort* __restrict__ Xhi,
                                                 const ushort* __restrict__ Xlo,
                                                 float* __restrict__ C,
                                                 int n, int K) {
    __shared__ ushort Ah[128][32], Al[128][32], Bh[128][32], Bl[128][32];
    const int tid = threadIdx.x;
    const int lane = tid & 63;
    const int wv = tid >> 6;
    const int wr = wv >> 1, wc = wv & 1;

    // triangular decode: block t -> (ti >= tj)
    const int t = blockIdx.x;
    int ti = (int)((sqrtf(8.0f * (float)t + 1.0f) - 1.0f) * 0.5f);
    while ((ti + 1) * (ti + 2) / 2 <= t) ++ti;
    while (ti * (ti + 1) / 2 > t) --ti;
    const int tj = t - ti * (ti + 1) / 2;
    const int bm = ti * 128, bn = tj * 128;

    f32x16 acc[2][2];
#pragma unroll
    for (int m = 0; m < 2; ++m)
#pragma unroll
        for (int q = 0; q < 2; ++q)
#pragma unroll
            for (int j = 0; j < 16; ++j) acc[m][q][j] = 0.f;

    const int srow = lane >> 2;
    const int scol = (lane & 3) * 8;
    const size_t rA0 = (size_t)(bm + wv * 16 + srow) * K;
    const size_t rA1 = (size_t)(bm + 64 + wv * 16 + srow) * K;
    const size_t rB0 = (size_t)(bn + wv * 16 + srow) * K;
    const size_t rB1 = (size_t)(bn + 64 + wv * 16 + srow) * K;

    // fragment addressing for 32x32x16: row = lane&31, k-base = (lane>>5)*8
    const int fr = lane & 31;
    const int kb = (lane >> 5) * 8;

    for (int k0 = 0; k0 < K; k0 += 32) {
        gload_lds16(Xhi + rA0 + k0 + scol, &Ah[wv * 16][0]);
        gload_lds16(Xhi + rA1 + k0 + scol, &Ah[64 + wv * 16][0]);
        gload_lds16(Xlo + rA0 + k0 + scol, &Al[wv * 16][0]);
        gload_lds16(Xlo + rA1 + k0 + scol, &Al[64 + wv * 16][0]);
        gload_lds16(Xhi + rB0 + k0 + scol, &Bh[wv * 16][0]);
        gload_lds16(Xhi + rB1 + k0 + scol, &Bh[64 + wv * 16][0]);
        gload_lds16(Xlo + rB0 + k0 + scol, &Bl[wv * 16][0]);
        gload_lds16(Xlo + rB1 + k0 + scol, &Bl[64 + wv * 16][0]);
        __syncthreads();

        bf16x8 ah[2][2], al[2][2], bh[2][2], bl[2][2];   // [m or q][ks]
#pragma unroll
        for (int m = 0; m < 2; ++m)
#pragma unroll
            for (int ks = 0; ks < 2; ++ks) {
                ah[m][ks] = *(const bf16x8*)&Ah[wr * 64 + m * 32 + fr][kb + ks * 16];
                al[m][ks] = *(const bf16x8*)&Al[wr * 64 + m * 32 + fr][kb + ks * 16];
                bh[m][ks] = *(const bf16x8*)&Bh[wc * 64 + m * 32 + fr][kb + ks * 16];
                bl[m][ks] = *(const bf16x8*)&Bl[wc * 64 + m * 32 + fr][kb + ks * 16];
            }
#pragma unroll
        for (int m = 0; m < 2; ++m)
#pragma unroll
            for (int q = 0; q < 2; ++q)
#pragma unroll
                for (int ks = 0; ks < 2; ++ks) {
                    acc[m][q] = __builtin_amdgcn_mfma_f32_32x32x16_bf16(ah[m][ks], bh[q][ks], acc[m][q], 0, 0, 0);
                    acc[m][q] = __builtin_amdgcn_mfma_f32_32x32x16_bf16(ah[m][ks], bl[q][ks], acc[m][q], 0, 0, 0);
                    acc[m][q] = __builtin_amdgcn_mfma_f32_32x32x16_bf16(al[m][ks], bh[q][ks], acc[m][q], 0, 0, 0);
                }
        __syncthreads();
    }

    // store: row = (reg&3) + 8*(reg>>2) + 4*(lane>>5), col = lane&31
    const int cc = lane & 31;
    const int rh = 4 * (lane >> 5);
    const bool offdiag = (bm != bn);
#pragma unroll
    for (int m = 0; m < 2; ++m)
#pragma unroll
        for (int q = 0; q < 2; ++q) {
            const int rbase = bm + wr * 64 + m * 32 + rh;
            const int c0 = bn + wc * 64 + q * 32 + cc;
#pragma unroll
            for (int g = 0; g < 4; ++g) {
                const int r0 = rbase + 8 * g;
#pragma unroll
                for (int j = 0; j < 4; ++j)
                    C[(size_t)(r0 + j) * n + c0] = acc[m][q][g * 4 + j];
                if (offdiag) {
                    float4 tv;
                    tv.x = acc[m][q][g * 4 + 0]; tv.y = acc[m][q][g * 4 + 1];
                    tv.z = acc[m][q][g * 4 + 2]; tv.w = acc[m][q][g * 4 + 3];
                    *(float4*)&C[(size_t)c0 * n + r0] = tv;   // r0 % 4 == 0 -> aligned
                }
            }
        }
}

// ---------------------------------------------------------------------------
// Fallback f32 vector GEMM (only if ws too small)
// ---------------------------------------------------------------------------
#define BM 128
#define BN 128
#define BKK 16

__global__ __launch_bounds__(256) void gemm_xxt(const float* __restrict__ X,
                                                float* __restrict__ C,
                                                int n, int K) {
    __shared__ float As[BKK][BM];
    __shared__ float Bs[BKK][BN];
    const int tid = threadIdx.x;
    const int tx = tid & 15;
    const int ty = tid >> 4;
    const int bm = blockIdx.y * BM;
    const int bn = blockIdx.x * BN;

    float acc[8][8];
#pragma unroll
    for (int p = 0; p < 8; ++p)
#pragma unroll
        for (int q = 0; q < 8; ++q) acc[p][q] = 0.0f;

    for (int k0 = 0; k0 < K; k0 += BKK) {
        for (int l = tid; l < BM * BKK / 4; l += 256) {
            int m = l >> 2;
            int kq = (l & 3) << 2;
            const float4 v = *(const float4*)(X + (size_t)(bm + m) * K + k0 + kq);
            As[kq + 0][m] = v.x; As[kq + 1][m] = v.y;
            As[kq + 2][m] = v.z; As[kq + 3][m] = v.w;
        }
        for (int l = tid; l < BN * BKK / 4; l += 256) {
            int m = l >> 2;
            int kq = (l & 3) << 2;
            const float4 v = *(const float4*)(X + (size_t)(bn + m) * K + k0 + kq);
            Bs[kq + 0][m] = v.x; Bs[kq + 1][m] = v.y;
            Bs[kq + 2][m] = v.z; Bs[kq + 3][m] = v.w;
        }
        __syncthreads();
#pragma unroll
        for (int kk = 0; kk < BKK; ++kk) {
            float a[8], b[8];
#pragma unroll
            for (int p = 0; p < 8; ++p) a[p] = As[kk][p * 16 + ty];
#pragma unroll
            for (int q = 0; q < 8; ++q) b[q] = Bs[kk][q * 16 + tx];
#pragma unroll
            for (int p = 0; p < 8; ++p)
#pragma unroll
                for (int q = 0; q < 8; ++q)
                    acc[p][q] = fmaf(a[p], b[q], acc[p][q]);
        }
        __syncthreads();
    }

    for (int p = 0; p < 8; ++p) {
        int r = bm + p * 16 + ty;
        for (int q = 0; q < 8; ++q) {
            C[(size_t)r * n + bn + q * 16 + tx] = acc[p][q];
        }
    }
}

// ---------------------------------------------------------------------------
// Lane-local Batcher odd-even mergesort of v[64], ascending, fully static
// ---------------------------------------------------------------------------
template <int I, int J>
__device__ __forceinline__ void ce_st(float (&v)[64]) {
    float a = v[I], b = v[J];
    v[I] = fminf(a, b);
    v[J] = fmaxf(a, b);
}

template <int I, int END, int STEP, int R>
struct CELoop {
    static __device__ __forceinline__ void run(float (&v)[64]) {
        if constexpr (I < END) {
            ce_st<I, I + R>(v);
            CELoop<I + STEP, END, STEP, R>::run(v);
        }
    }
};

template <int LO, int N, int R>
struct OEMerge {
    static __device__ __forceinline__ void run(float (&v)[64]) {
        constexpr int M = R * 2;
        if constexpr (M < N) {
            OEMerge<LO, N, M>::run(v);
            OEMerge<LO + R, N, M>::run(v);
            CELoop<LO + R, LO + N - R, M, R>::run(v);
        } else {
            ce_st<LO, LO + R>(v);
        }
    }
};

template <int LO, int N>
struct OESort {
    static __device__ __forceinline__ void run(float (&v)[64]) {
        if constexpr (N > 1) {
            OESort<LO, N / 2>::run(v);
            OESort<LO + N / 2, N / 2>::run(v);
            OEMerge<LO, N, 1>::run(v);
        }
    }
};

// ---------------------------------------------------------------------------
// Cross-lane merge with DPP/swizzle-lowered exchanges (validated r7)
// ---------------------------------------------------------------------------
template <int S>
__device__ __forceinline__ void regclean(float (&v)[64]) {
    if constexpr (S >= 1) {
#pragma unroll
        for (int r = 0; r < 64; ++r) {
            if ((r & S) == 0) {
                float a = v[r], b = v[r | S];
                v[r] = fminf(a, b);
                v[r | S] = fmaxf(a, b);
            }
        }
        regclean<(S >> 1)>(v);
    }
}

template <int T>
__device__ __forceinline__ void lanestride_clean(float (&v)[64], const int lane) {
    if constexpr (T >= 1) {
        const bool keepmin = (lane & T) == 0;
#pragma unroll
        for (int r = 0; r < 64; ++r) {
            float o = lxorf<T>(v[r]);
            float mn = fminf(v[r], o), mx = fmaxf(v[r], o);
            v[r] = keepmin ? mn : mx;
        }
        lanestride_clean<(T >> 1)>(v, lane);
    }
}

template <int G>
__device__ __forceinline__ void xmerge(float (&v)[64], const int lane) {
    const bool fh = (lane & (G >> 1)) == 0;
#pragma unroll
    for (int r = 0; r < 32; ++r) {
        float oA = lxorf<G - 1>(v[63 - r]);
        float oB = lxorf<G - 1>(v[r]);
        float a = v[r], b = v[63 - r];
        v[r]      = fh ? fminf(a, oA) : fmaxf(a, oA);
        v[63 - r] = fh ? fminf(b, oB) : fmaxf(b, oB);
    }
    lanestride_clean<(G >> 2)>(v, lane);
    regclean<32>(v);
}

// ---------------------------------------------------------------------------
// Threefry pairing (validated round 6)
// ---------------------------------------------------------------------------
template <bool LOW>
__device__ __forceinline__ void score_phase1(float (&v)[64], float (&sc)[64],
                                             float* wbuf, const int lane,
                                             const int rowlow, const float m,
                                             const float denom) {
    constexpr int RB = LOW ? 0 : 32;
#pragma unroll
    for (int rr = 0; rr < 32; ++rr) {
        const int r = RB + rr;
        uint32_t f = (uint32_t)(rowlow * NEGN + lane * 64 + r);
        uint32_t x0 = f, x1 = f + HHALF;
        threefry2x32(0u, 42u, x0, x1);
        float gown = gumbel_from_bits(LOW ? x0 : x1);
        float gpart = gumbel_from_bits(LOW ? x1 : x0);
        wbuf[lane * 33 + rr] = gpart;
        bool valid = (r < 56) || (lane < 63);
        float d = v[r] - m;
        sc[r] = valid ? (d * d) / denom + gown : -INFINITY;
    }
}

template <bool LOW>
__device__ __forceinline__ void score_phase2(float (&v)[64], float (&sc)[64],
                                             const float* rbuf, const int lane,
                                             const float m, const float denom) {
    constexpr int RB = LOW ? 32 : 0;
#pragma unroll
    for (int rr = 0; rr < 32; ++rr) {
        const int r = RB + rr;
        float g = rbuf[lane * 33 + rr];
        bool valid = (r < 56) || (lane < 63);
        float d = v[r] - m;
        sc[r] = valid ? (d * d) / denom + g : -INFINITY;
    }
}

// ---------------------------------------------------------------------------
// Per-row kernel (validated round 7, unchanged)
// ---------------------------------------------------------------------------
__global__ __launch_bounds__(256, 1) void row_kernel(const float* __restrict__ sim,
                                                     float* __restrict__ row_out) {
    __shared__ float bufL[2][64 * 33];
    __shared__ float bufH[2][64 * 33];

    const int lane = threadIdx.x & 63;
    const int wv = threadIdx.x >> 6;
    const bool low = (wv < 2);
    const int p = wv & 1;
    const int rowlow = blockIdx.x * 2 + p;
    const int row = low ? rowlow : rowlow + 2048;
    const float* simrow = sim + (size_t)row * NROW;
    const int base = row & ~(KCLS - 1);
    const int posrq = base >> 8;

    float v[64];
    float nsum = 0.0f, psum = 0.0f, plos = 0.0f, pmax = -INFINITY;

#pragma unroll
    for (int rq = 0; rq < 16; ++rq) {
        const float4 w4 = *(const float4*)(simrow + rq * 256 + lane * 4);
        float e[4] = {w4.x, w4.y, w4.z, w4.w};
        if (rq == posrq) {
#pragma unroll
            for (int c = 0; c < 4; ++c) {
                int col = rq * 256 + lane * 4 + c;
                float val = e[c];
                bool ispos = (col >= base) && (col < base + KCLS);
                if (ispos) {
                    if (col != row) {
                        psum += val;
                        pmax = fmaxf(pmax, val);
                        plos += softplus_f(-2.0f * (val - 0.5f));
                    }
                    v[rq * 4 + c] = INFINITY;
                } else {
                    nsum += val;
                    v[rq * 4 + c] = val;
                }
            }
        } else {
#pragma unroll
            for (int c = 0; c < 4; ++c) {
                nsum += e[c];
                v[rq * 4 + c] = e[c];
            }
        }
    }

#define BSTEP(M)                                   \
    nsum += lxorf<M>(nsum);                        \
    psum += lxorf<M>(psum);                        \
    plos += lxorf<M>(plos);                        \
    pmax = fmaxf(pmax, lxorf<M>(pmax));
    BSTEP(1) BSTEP(2) BSTEP(4) BSTEP(8) BSTEP(16) BSTEP(32)
#undef BSTEP
    const float m = nsum / (float)NEGN;

    OESort<0, 64>::run(v);
    xmerge<2>(v, lane);
    xmerge<4>(v, lane);
    xmerge<8>(v, lane);
    xmerge<16>(v, lane);
    xmerge<32>(v, lane);
    xmerge<64>(v, lane);

    float vs = 0.0f;
#pragma unroll
    for (int r = 0; r < 64; ++r) {
        bool valid = (r < 56) || (lane < 63);
        float d = v[r] - m;
        vs += valid ? d * d : 0.0f;
    }
    vs += lxorf<1>(vs); vs += lxorf<2>(vs); vs += lxorf<4>(vs);
    vs += lxorf<8>(vs); vs += lxorf<16>(vs); vs += lxorf<32>(vs);
    const float var = vs / (float)NEGN;
    const float sd = sqrtf(var);
    const float denom = 2.0f * sd * sd;

    float sc[64];
    if (low) score_phase1<true>(v, sc, &bufL[p][0], lane, rowlow, m, denom);
    else     score_phase1<false>(v, sc, &bufH[p][0], lane, rowlow, m, denom);
    __syncthreads();
    if (low) score_phase2<true>(v, sc, &bufH[p][0], lane, m, denom);
    else     score_phase2<false>(v, sc, &bufL[p][0], lane, m, denom);

    float nl = 0.0f, neg_last = 0.0f;
    const int lb = lane * 64;
    for (int t = 0; t < 7; ++t) {
        float bs4[4], bv4[4];
        int bi4[4];
#pragma unroll
        for (int g = 0; g < 4; ++g) { bs4[g] = -INFINITY; bv4[g] = 0.f; bi4[g] = 0x7fffffff; }
#pragma unroll
        for (int j = 0; j < 16; ++j) {
#pragma unroll
            for (int g = 0; g < 4; ++g) {
                const int r = g * 16 + j;
                if (sc[r] > bs4[g]) { bs4[g] = sc[r]; bv4[g] = v[r]; bi4[g] = lb + r; }
            }
        }
        float bs = bs4[0], bv = bv4[0];
        int bi = bi4[0];
#pragma unroll
        for (int g = 1; g < 4; ++g) {
            if (bs4[g] > bs) { bs = bs4[g]; bv = bv4[g]; bi = bi4[g]; }
        }
#define TSTEP(M)                                                          \
        {                                                                 \
            float os = lxorf<M>(bs);                                      \
            float ov = lxorf<M>(bv);                                      \
            int oi = lxori<M>(bi);                                        \
            if (os > bs || (os == bs && oi < bi)) { bs = os; bv = ov; bi = oi; } \
        }
        TSTEP(1) TSTEP(2) TSTEP(4) TSTEP(8) TSTEP(16) TSTEP(32)
#undef TSTEP
        nl += softplus_f(50.0f * (bv - 0.5f));
        if (t == 6) neg_last = bv;
        const int bl = bi - lb;
#pragma unroll
        for (int r = 0; r < 64; ++r)
            if (r == bl) sc[r] = -INFINITY;
    }

    if (lane == 0) {
        float pos_loss = plos / (float)(KCLS - 1);
        float neg_loss = 0.04f * (nl / (float)(KCLS - 1));
        row_out[row * 4 + 0] = pos_loss + neg_loss;
        row_out[row * 4 + 1] = (pmax > neg_last + 0.05f) ? 1.0f : 0.0f;
        row_out[row * 4 + 2] = psum;
        row_out[row * 4 + 3] = nsum;
    }
}

// ---------------------------------------------------------------------------
// Deterministic final reduction (single block, f64 accumulation)
// ---------------------------------------------------------------------------
__global__ __launch_bounds__(256) void reduce_kernel(const float* __restrict__ row_out,
                                                     float* __restrict__ out,
                                                     int n, int k) {
    __shared__ double sh[4][256];
    const int tid = threadIdx.x;
    double a = 0.0, b = 0.0, c = 0.0, d = 0.0;
    for (int i = tid; i < n; i += 256) {
        a += (double)row_out[i * 4 + 0];
        b += (double)row_out[i * 4 + 1];
        c += (double)row_out[i * 4 + 2];
        d += (double)row_out[i * 4 + 3];
    }
    sh[0][tid] = a; sh[1][tid] = b; sh[2][tid] = c; sh[3][tid] = d;
    __syncthreads();
    for (int off = 128; off; off >>= 1) {
        if (tid < off) {
            sh[0][tid] += sh[0][tid + off];
            sh[1][tid] += sh[1][tid + off];
            sh[2][tid] += sh[2][tid + off];
            sh[3][tid] += sh[3][tid + off];
        }
        __syncthreads();
    }
    if (tid == 0) {
        out[0] = (float)(sh[0][0] / (double)n);
        out[1] = (float)(sh[1][0] / (double)n);
        out[2] = (float)(sh[2][0] / ((double)n * (double)(k - 1)));
        out[3] = (float)(sh[3][0] / ((double)n * (double)(n - k)));
    }
}

// ---------------------------------------------------------------------------
extern "C" void kernel_launch(void* const* d_in, const int* in_sizes, int n_in,
                              void* d_out, int out_size, void* d_ws, size_t ws_size,
                              hipStream_t stream) {
    const float* X = (const float*)d_in[0];
    const int n = in_sizes[1];            // 4096
    const int K = in_sizes[0] / n;        // 1024
    const int k = 8;

    const size_t simB = (size_t)n * n * sizeof(float);
    const size_t rowB = (size_t)n * 4 * sizeof(float);
    float* sim = (float*)d_ws;
    float* row_out = (float*)((char*)d_ws + simB);
    ushort* Xhi = (ushort*)((char*)d_ws + simB + rowB);
    ushort* Xlo = Xhi + (size_t)n * K;
    const size_t need = simB + rowB + (size_t)n * K * 2 * sizeof(ushort);

    if (ws_size >= need) {
        const int total4 = n * K / 4;
        convert_kernel<<<(total4 + 255) / 256, 256, 0, stream>>>(X, Xhi, Xlo, total4);
        const int nt = n / 128;
        gemm_mfma<<<nt * (nt + 1) / 2, 256, 0, stream>>>(Xhi, Xlo, sim, n, K);
    } else {
        dim3 gg(n / BN, n / BM);
        gemm_xxt<<<gg, 256, 0, stream>>>(X, sim, n, K);
    }
    row_kernel<<<n / 4, 256, 0, stream>>>(sim, row_out);
    reduce_kernel<<<1, 256, 0, stream>>>(row_out, (float*)d_out, n, k);
}

// Round 10
// 243.060 us; speedup vs baseline: 1.0263x; 1.0263x over previous
//
#include <hip/hip_runtime.h>
#include <hip/hip_bf16.h>
#include <math.h>
#include <stdint.h>

typedef short bf16x8 __attribute__((ext_vector_type(8)));
typedef float f32x4 __attribute__((ext_vector_type(4)));

#define NROW 4096
#define NEGN 4088
#define KCLS 8
#define HHALF 8372224u

// ---------------------------------------------------------------------------
// Threefry2x32 (JAX-compatible) and gumbel mapping (validated rounds 0-9)
// ---------------------------------------------------------------------------
__device__ __forceinline__ uint32_t rotl32(uint32_t v, int r) {
    return (v << r) | (v >> (32 - r));
}

__device__ __forceinline__ void threefry2x32(uint32_t k0, uint32_t k1,
                                             uint32_t& x0, uint32_t& x1) {
    uint32_t ks[3] = {k0, k1, k0 ^ k1 ^ 0x1BD11BDAu};
    const int rot[2][4] = {{13, 15, 26, 6}, {17, 29, 16, 24}};
    x0 += ks[0];
    x1 += ks[1];
#pragma unroll
    for (int i = 0; i < 5; ++i) {
#pragma unroll
        for (int r = 0; r < 4; ++r) {
            x0 += x1;
            x1 = rotl32(x1, rot[i & 1][r]);
            x1 ^= x0;
        }
        x0 += ks[(i + 1) % 3];
        x1 += ks[(i + 2) % 3] + (uint32_t)(i + 1);
    }
}

__device__ __forceinline__ float gumbel_from_bits(uint32_t bits) {
    uint32_t fb = (bits >> 9) | 0x3f800000u;
    float u = __uint_as_float(fb) - 1.0f;
    const float tiny = 1.1754943508222875e-38f;
    u = u * (1.0f - tiny) + tiny;
    u = fmaxf(tiny, u);
    return -logf(-logf(u));
}

__device__ __forceinline__ float softplus_f(float x) {
    return fmaxf(x, 0.0f) + log1pf(expf(-fabsf(x)));
}

// ---------------------------------------------------------------------------
// Cross-lane XOR exchange with cheapest available lowering (validated r7)
// ---------------------------------------------------------------------------
template <int M>
__device__ __forceinline__ int lxori(int i) {
    if constexpr (M == 1 || M == 2 || M == 3 || M == 7 || M == 8 || M == 15) {
        constexpr int ctrl = (M == 1) ? 0xB1
                           : (M == 2) ? 0x4E
                           : (M == 3) ? 0x1B
                           : (M == 7) ? 0x141
                           : (M == 8) ? 0x128
                                      : 0x140;
        return __builtin_amdgcn_update_dpp(i, i, ctrl, 0xf, 0xf, false);
    } else if constexpr (M == 4 || M == 16) {
        constexpr int off = (M == 4) ? 0x101F : 0x401F;
        return __builtin_amdgcn_ds_swizzle(i, off);
    } else if constexpr (M == 31) {
        return lxori<16>(lxori<15>(i));
    } else {
        return __shfl_xor(i, M, 64);
    }
}

template <int M>
__device__ __forceinline__ float lxorf(float x) {
    return __int_as_float(lxori<M>(__float_as_int(x)));
}

// ---------------------------------------------------------------------------
// f32 -> bf16 hi/lo split (validated round 4)
// ---------------------------------------------------------------------------
__global__ __launch_bounds__(256) void convert_kernel(const float* __restrict__ X,
                                                      ushort* __restrict__ Xhi,
                                                      ushort* __restrict__ Xlo,
                                                      int total4) {
    int i = blockIdx.x * 256 + threadIdx.x;
    if (i >= total4) return;
    float4 x = ((const float4*)X)[i];
    float xs[4] = {x.x, x.y, x.z, x.w};
    ushort h[4], l[4];
#pragma unroll
    for (int j = 0; j < 4; ++j) {
        __hip_bfloat16 hb = __float2bfloat16(xs[j]);
        float hf = __bfloat162float(hb);
        __hip_bfloat16 lb = __float2bfloat16(xs[j] - hf);
        h[j] = *(ushort*)&hb;
        l[j] = *(ushort*)&lb;
    }
    ((ushort4*)Xhi)[i] = make_ushort4(h[0], h[1], h[2], h[3]);
    ((ushort4*)Xlo)[i] = make_ushort4(l[0], l[1], l[2], l[3]);
}

// ---------------------------------------------------------------------------
// MFMA GEMM, TRIANGULAR, 16x16x32 shape (round-8 validated best):
// only lower-triangle tiles (i >= j); off-diagonal tiles mirror into the
// upper triangle via float4 stores. sim = Hi*Hi^T + Hi*Lo^T + Lo*Hi^T.
// ---------------------------------------------------------------------------
__device__ __forceinline__ void gload_lds16(const void* g, void* l) {
    __builtin_amdgcn_global_load_lds((const __attribute__((address_space(1))) void*)g,
                                     (__attribute__((address_space(3))) void*)l, 16, 0, 0);
}

__global__ __launch_bounds__(256) void gemm_mfma(const ushort* __restrict__ Xhi,
                                                 const ushort* __restrict__ Xlo,
                                                 float* __restrict__ C,
                                                 int n, int K) {
    __shared__ ushort Ah[128][32], Al[128][32], Bh[128][32], Bl[128][32];
    const int tid = threadIdx.x;
    const int lane = tid & 63;
    const int wv = tid >> 6;
    const int wr = wv >> 1, wc = wv & 1;

    // triangular decode: block t -> (ti >= tj)
    const int t = blockIdx.x;
    int ti = (int)((sqrtf(8.0f * (float)t + 1.0f) - 1.0f) * 0.5f);
    while ((ti + 1) * (ti + 2) / 2 <= t) ++ti;
    while (ti * (ti + 1) / 2 > t) --ti;
    const int tj = t - ti * (ti + 1) / 2;
    const int bm = ti * 128, bn = tj * 128;

    f32x4 acc[4][4];
#pragma unroll
    for (int m = 0; m < 4; ++m)
#pragma unroll
        for (int q = 0; q < 4; ++q) acc[m][q] = {0.f, 0.f, 0.f, 0.f};

    const int srow = lane >> 2;
    const int scol = (lane & 3) * 8;
    const size_t rA0 = (size_t)(bm + wv * 16 + srow) * K;
    const size_t rA1 = (size_t)(bm + 64 + wv * 16 + srow) * K;
    const size_t rB0 = (size_t)(bn + wv * 16 + srow) * K;
    const size_t rB1 = (size_t)(bn + 64 + wv * 16 + srow) * K;

    for (int k0 = 0; k0 < K; k0 += 32) {
        gload_lds16(Xhi + rA0 + k0 + scol, &Ah[wv * 16][0]);
        gload_lds16(Xhi + rA1 + k0 + scol, &Ah[64 + wv * 16][0]);
        gload_lds16(Xlo + rA0 + k0 + scol, &Al[wv * 16][0]);
        gload_lds16(Xlo + rA1 + k0 + scol, &Al[64 + wv * 16][0]);
        gload_lds16(Xhi + rB0 + k0 + scol, &Bh[wv * 16][0]);
        gload_lds16(Xhi + rB1 + k0 + scol, &Bh[64 + wv * 16][0]);
        gload_lds16(Xlo + rB0 + k0 + scol, &Bl[wv * 16][0]);
        gload_lds16(Xlo + rB1 + k0 + scol, &Bl[64 + wv * 16][0]);
        __syncthreads();

        bf16x8 ah[4], al[4], bh[4], bl[4];
        const int fr = lane & 15;
        const int kc = (lane >> 4) * 8;
#pragma unroll
        for (int m = 0; m < 4; ++m) {
            ah[m] = *(const bf16x8*)&Ah[wr * 64 + m * 16 + fr][kc];
            al[m] = *(const bf16x8*)&Al[wr * 64 + m * 16 + fr][kc];
            bh[m] = *(const bf16x8*)&Bh[wc * 64 + m * 16 + fr][kc];
            bl[m] = *(const bf16x8*)&Bl[wc * 64 + m * 16 + fr][kc];
        }
#pragma unroll
        for (int m = 0; m < 4; ++m)
#pragma unroll
            for (int q = 0; q < 4; ++q) {
                acc[m][q] = __builtin_amdgcn_mfma_f32_16x16x32_bf16(ah[m], bh[q], acc[m][q], 0, 0, 0);
                acc[m][q] = __builtin_amdgcn_mfma_f32_16x16x32_bf16(ah[m], bl[q], acc[m][q], 0, 0, 0);
                acc[m][q] = __builtin_amdgcn_mfma_f32_16x16x32_bf16(al[m], bh[q], acc[m][q], 0, 0, 0);
            }
        __syncthreads();
    }

    // C/D layout (m89-verified): col = lane&15, row = (lane>>4)*4 + reg
    const int cr = (lane >> 4) * 4;
    const int cc = lane & 15;
    const bool offdiag = (bm != bn);
#pragma unroll
    for (int m = 0; m < 4; ++m)
#pragma unroll
        for (int q = 0; q < 4; ++q) {
            const int r0 = bm + wr * 64 + m * 16 + cr;
            const int c0 = bn + wc * 64 + q * 16 + cc;
#pragma unroll
            for (int j = 0; j < 4; ++j)
                C[(size_t)(r0 + j) * n + c0] = acc[m][q][j];
            if (offdiag) {
                float4 tv;
                tv.x = acc[m][q][0]; tv.y = acc[m][q][1];
                tv.z = acc[m][q][2]; tv.w = acc[m][q][3];
                *(float4*)&C[(size_t)c0 * n + r0] = tv;   // r0 % 4 == 0 -> aligned
            }
        }
}

// ---------------------------------------------------------------------------
// Fallback f32 vector GEMM (only if ws too small)
// ---------------------------------------------------------------------------
#define BM 128
#define BN 128
#define BKK 16

__global__ __launch_bounds__(256) void gemm_xxt(const float* __restrict__ X,
                                                float* __restrict__ C,
                                                int n, int K) {
    __shared__ float As[BKK][BM];
    __shared__ float Bs[BKK][BN];
    const int tid = threadIdx.x;
    const int tx = tid & 15;
    const int ty = tid >> 4;
    const int bm = blockIdx.y * BM;
    const int bn = blockIdx.x * BN;

    float acc[8][8];
#pragma unroll
    for (int p = 0; p < 8; ++p)
#pragma unroll
        for (int q = 0; q < 8; ++q) acc[p][q] = 0.0f;

    for (int k0 = 0; k0 < K; k0 += BKK) {
        for (int l = tid; l < BM * BKK / 4; l += 256) {
            int m = l >> 2;
            int kq = (l & 3) << 2;
            const float4 v = *(const float4*)(X + (size_t)(bm + m) * K + k0 + kq);
            As[kq + 0][m] = v.x; As[kq + 1][m] = v.y;
            As[kq + 2][m] = v.z; As[kq + 3][m] = v.w;
        }
        for (int l = tid; l < BN * BKK / 4; l += 256) {
            int m = l >> 2;
            int kq = (l & 3) << 2;
            const float4 v = *(const float4*)(X + (size_t)(bn + m) * K + k0 + kq);
            Bs[kq + 0][m] = v.x; Bs[kq + 1][m] = v.y;
            Bs[kq + 2][m] = v.z; Bs[kq + 3][m] = v.w;
        }
        __syncthreads();
#pragma unroll
        for (int kk = 0; kk < BKK; ++kk) {
            float a[8], b[8];
#pragma unroll
            for (int p = 0; p < 8; ++p) a[p] = As[kk][p * 16 + ty];
#pragma unroll
            for (int q = 0; q < 8; ++q) b[q] = Bs[kk][q * 16 + tx];
#pragma unroll
            for (int p = 0; p < 8; ++p)
#pragma unroll
                for (int q = 0; q < 8; ++q)
                    acc[p][q] = fmaf(a[p], b[q], acc[p][q]);
        }
        __syncthreads();
    }

    for (int p = 0; p < 8; ++p) {
        int r = bm + p * 16 + ty;
        for (int q = 0; q < 8; ++q) {
            C[(size_t)r * n + bn + q * 16 + tx] = acc[p][q];
        }
    }
}

// ---------------------------------------------------------------------------
// Lane-local Batcher odd-even mergesort of v[64], ascending, fully static
// ---------------------------------------------------------------------------
template <int I, int J>
__device__ __forceinline__ void ce_st(float (&v)[64]) {
    float a = v[I], b = v[J];
    v[I] = fminf(a, b);
    v[J] = fmaxf(a, b);
}

template <int I, int END, int STEP, int R>
struct CELoop {
    static __device__ __forceinline__ void run(float (&v)[64]) {
        if constexpr (I < END) {
            ce_st<I, I + R>(v);
            CELoop<I + STEP, END, STEP, R>::run(v);
        }
    }
};

template <int LO, int N, int R>
struct OEMerge {
    static __device__ __forceinline__ void run(float (&v)[64]) {
        constexpr int M = R * 2;
        if constexpr (M < N) {
            OEMerge<LO, N, M>::run(v);
            OEMerge<LO + R, N, M>::run(v);
            CELoop<LO + R, LO + N - R, M, R>::run(v);
        } else {
            ce_st<LO, LO + R>(v);
        }
    }
};

template <int LO, int N>
struct OESort {
    static __device__ __forceinline__ void run(float (&v)[64]) {
        if constexpr (N > 1) {
            OESort<LO, N / 2>::run(v);
            OESort<LO + N / 2, N / 2>::run(v);
            OEMerge<LO, N, 1>::run(v);
        }
    }
};

// ---------------------------------------------------------------------------
// Cross-lane merge with DPP/swizzle-lowered exchanges (validated r7)
// ---------------------------------------------------------------------------
template <int S>
__device__ __forceinline__ void regclean(float (&v)[64]) {
    if constexpr (S >= 1) {
#pragma unroll
        for (int r = 0; r < 64; ++r) {
            if ((r & S) == 0) {
                float a = v[r], b = v[r | S];
                v[r] = fminf(a, b);
                v[r | S] = fmaxf(a, b);
            }
        }
        regclean<(S >> 1)>(v);
    }
}

template <int T>
__device__ __forceinline__ void lanestride_clean(float (&v)[64], const int lane) {
    if constexpr (T >= 1) {
        const bool keepmin = (lane & T) == 0;
#pragma unroll
        for (int r = 0; r < 64; ++r) {
            float o = lxorf<T>(v[r]);
            float mn = fminf(v[r], o), mx = fmaxf(v[r], o);
            v[r] = keepmin ? mn : mx;
        }
        lanestride_clean<(T >> 1)>(v, lane);
    }
}

template <int G>
__device__ __forceinline__ void xmerge(float (&v)[64], const int lane) {
    const bool fh = (lane & (G >> 1)) == 0;
#pragma unroll
    for (int r = 0; r < 32; ++r) {
        float oA = lxorf<G - 1>(v[63 - r]);
        float oB = lxorf<G - 1>(v[r]);
        float a = v[r], b = v[63 - r];
        v[r]      = fh ? fminf(a, oA) : fmaxf(a, oA);
        v[63 - r] = fh ? fminf(b, oB) : fmaxf(b, oB);
    }
    lanestride_clean<(G >> 2)>(v, lane);
    regclean<32>(v);
}

// ---------------------------------------------------------------------------
// Threefry pairing (validated round 6)
// ---------------------------------------------------------------------------
template <bool LOW>
__device__ __forceinline__ void score_phase1(float (&v)[64], float (&sc)[64],
                                             float* wbuf, const int lane,
                                             const int rowlow, const float m,
                                             const float denom) {
    constexpr int RB = LOW ? 0 : 32;
#pragma unroll
    for (int rr = 0; rr < 32; ++rr) {
        const int r = RB + rr;
        uint32_t f = (uint32_t)(rowlow * NEGN + lane * 64 + r);
        uint32_t x0 = f, x1 = f + HHALF;
        threefry2x32(0u, 42u, x0, x1);
        float gown = gumbel_from_bits(LOW ? x0 : x1);
        float gpart = gumbel_from_bits(LOW ? x1 : x0);
        wbuf[lane * 33 + rr] = gpart;
        bool valid = (r < 56) || (lane < 63);
        float d = v[r] - m;
        sc[r] = valid ? (d * d) / denom + gown : -INFINITY;
    }
}

template <bool LOW>
__device__ __forceinline__ void score_phase2(float (&v)[64], float (&sc)[64],
                                             const float* rbuf, const int lane,
                                             const float m, const float denom) {
    constexpr int RB = LOW ? 32 : 0;
#pragma unroll
    for (int rr = 0; rr < 32; ++rr) {
        const int r = RB + rr;
        float g = rbuf[lane * 33 + rr];
        bool valid = (r < 56) || (lane < 63);
        float d = v[r] - m;
        sc[r] = valid ? (d * d) / denom + g : -INFINITY;
    }
}

// ---------------------------------------------------------------------------
// Per-row kernel (validated round 7, unchanged)
// ---------------------------------------------------------------------------
__global__ __launch_bounds__(256, 1) void row_kernel(const float* __restrict__ sim,
                                                     float* __restrict__ row_out) {
    __shared__ float bufL[2][64 * 33];
    __shared__ float bufH[2][64 * 33];

    const int lane = threadIdx.x & 63;
    const int wv = threadIdx.x >> 6;
    const bool low = (wv < 2);
    const int p = wv & 1;
    const int rowlow = blockIdx.x * 2 + p;
    const int row = low ? rowlow : rowlow + 2048;
    const float* simrow = sim + (size_t)row * NROW;
    const int base = row & ~(KCLS - 1);
    const int posrq = base >> 8;

    float v[64];
    float nsum = 0.0f, psum = 0.0f, plos = 0.0f, pmax = -INFINITY;

#pragma unroll
    for (int rq = 0; rq < 16; ++rq) {
        const float4 w4 = *(const float4*)(simrow + rq * 256 + lane * 4);
        float e[4] = {w4.x, w4.y, w4.z, w4.w};
        if (rq == posrq) {
#pragma unroll
            for (int c = 0; c < 4; ++c) {
                int col = rq * 256 + lane * 4 + c;
                float val = e[c];
                bool ispos = (col >= base) && (col < base + KCLS);
                if (ispos) {
                    if (col != row) {
                        psum += val;
                        pmax = fmaxf(pmax, val);
                        plos += softplus_f(-2.0f * (val - 0.5f));
                    }
                    v[rq * 4 + c] = INFINITY;
                } else {
                    nsum += val;
                    v[rq * 4 + c] = val;
                }
            }
        } else {
#pragma unroll
            for (int c = 0; c < 4; ++c) {
                nsum += e[c];
                v[rq * 4 + c] = e[c];
            }
        }
    }

#define BSTEP(M)                                   \
    nsum += lxorf<M>(nsum);                        \
    psum += lxorf<M>(psum);                        \
    plos += lxorf<M>(plos);                        \
    pmax = fmaxf(pmax, lxorf<M>(pmax));
    BSTEP(1) BSTEP(2) BSTEP(4) BSTEP(8) BSTEP(16) BSTEP(32)
#undef BSTEP
    const float m = nsum / (float)NEGN;

    OESort<0, 64>::run(v);
    xmerge<2>(v, lane);
    xmerge<4>(v, lane);
    xmerge<8>(v, lane);
    xmerge<16>(v, lane);
    xmerge<32>(v, lane);
    xmerge<64>(v, lane);

    float vs = 0.0f;
#pragma unroll
    for (int r = 0; r < 64; ++r) {
        bool valid = (r < 56) || (lane < 63);
        float d = v[r] - m;
        vs += valid ? d * d : 0.0f;
    }
    vs += lxorf<1>(vs); vs += lxorf<2>(vs); vs += lxorf<4>(vs);
    vs += lxorf<8>(vs); vs += lxorf<16>(vs); vs += lxorf<32>(vs);
    const float var = vs / (float)NEGN;
    const float sd = sqrtf(var);
    const float denom = 2.0f * sd * sd;

    float sc[64];
    if (low) score_phase1<true>(v, sc, &bufL[p][0], lane, rowlow, m, denom);
    else     score_phase1<false>(v, sc, &bufH[p][0], lane, rowlow, m, denom);
    __syncthreads();
    if (low) score_phase2<true>(v, sc, &bufH[p][0], lane, m, denom);
    else     score_phase2<false>(v, sc, &bufL[p][0], lane, m, denom);

    float nl = 0.0f, neg_last = 0.0f;
    const int lb = lane * 64;
    for (int t = 0; t < 7; ++t) {
        float bs4[4], bv4[4];
        int bi4[4];
#pragma unroll
        for (int g = 0; g < 4; ++g) { bs4[g] = -INFINITY; bv4[g] = 0.f; bi4[g] = 0x7fffffff; }
#pragma unroll
        for (int j = 0; j < 16; ++j) {
#pragma unroll
            for (int g = 0; g < 4; ++g) {
                const int r = g * 16 + j;
                if (sc[r] > bs4[g]) { bs4[g] = sc[r]; bv4[g] = v[r]; bi4[g] = lb + r; }
            }
        }
        float bs = bs4[0], bv = bv4[0];
        int bi = bi4[0];
#pragma unroll
        for (int g = 1; g < 4; ++g) {
            if (bs4[g] > bs) { bs = bs4[g]; bv = bv4[g]; bi = bi4[g]; }
        }
#define TSTEP(M)                                                          \
        {                                                                 \
            float os = lxorf<M>(bs);                                      \
            float ov = lxorf<M>(bv);                                      \
            int oi = lxori<M>(bi);                                        \
            if (os > bs || (os == bs && oi < bi)) { bs = os; bv = ov; bi = oi; } \
        }
        TSTEP(1) TSTEP(2) TSTEP(4) TSTEP(8) TSTEP(16) TSTEP(32)
#undef TSTEP
        nl += softplus_f(50.0f * (bv - 0.5f));
        if (t == 6) neg_last = bv;
        const int bl = bi - lb;
#pragma unroll
        for (int r = 0; r < 64; ++r)
            if (r == bl) sc[r] = -INFINITY;
    }

    if (lane == 0) {
        float pos_loss = plos / (float)(KCLS - 1);
        float neg_loss = 0.04f * (nl / (float)(KCLS - 1));
        row_out[row * 4 + 0] = pos_loss + neg_loss;
        row_out[row * 4 + 1] = (pmax > neg_last + 0.05f) ? 1.0f : 0.0f;
        row_out[row * 4 + 2] = psum;
        row_out[row * 4 + 3] = nsum;
    }
}

// ---------------------------------------------------------------------------
// Deterministic final reduction (single block, f64 accumulation)
// ---------------------------------------------------------------------------
__global__ __launch_bounds__(256) void reduce_kernel(const float* __restrict__ row_out,
                                                     float* __restrict__ out,
                                                     int n, int k) {
    __shared__ double sh[4][256];
    const int tid = threadIdx.x;
    double a = 0.0, b = 0.0, c = 0.0, d = 0.0;
    for (int i = tid; i < n; i += 256) {
        a += (double)row_out[i * 4 + 0];
        b += (double)row_out[i * 4 + 1];
        c += (double)row_out[i * 4 + 2];
        d += (double)row_out[i * 4 + 3];
    }
    sh[0][tid] = a; sh[1][tid] = b; sh[2][tid] = c; sh[3][tid] = d;
    __syncthreads();
    for (int off = 128; off; off >>= 1) {
        if (tid < off) {
            sh[0][tid] += sh[0][tid + off];
            sh[1][tid] += sh[1][tid + off];
            sh[2][tid] += sh[2][tid + off];
            sh[3][tid] += sh[3][tid + off];
        }
        __syncthreads();
    }
    if (tid == 0) {
        out[0] = (float)(sh[0][0] / (double)n);
        out[1] = (float)(sh[1][0] / (double)n);
        out[2] = (float)(sh[2][0] / ((double)n * (double)(k - 1)));
        out[3] = (float)(sh[3][0] / ((double)n * (double)(n - k)));
    }
}

// ---------------------------------------------------------------------------
extern "C" void kernel_launch(void* const* d_in, const int* in_sizes, int n_in,
                              void* d_out, int out_size, void* d_ws, size_t ws_size,
                              hipStream_t stream) {
    const float* X = (const float*)d_in[0];
    const int n = in_sizes[1];            // 4096
    const int K = in_sizes[0] / n;        // 1024
    const int k = 8;

    const size_t simB = (size_t)n * n * sizeof(float);
    const size_t rowB = (size_t)n * 4 * sizeof(float);
    float* sim = (float*)d_ws;
    float* row_out = (float*)((char*)d_ws + simB);
    ushort* Xhi = (ushort*)((char*)d_ws + simB + rowB);
    ushort* Xlo = Xhi + (size_t)n * K;
    const size_t need = simB + rowB + (size_t)n * K * 2 * sizeof(ushort);

    if (ws_size >= need) {
        const int total4 = n * K / 4;
        convert_kernel<<<(total4 + 255) / 256, 256, 0, stream>>>(X, Xhi, Xlo, total4);
        const int nt = n / 128;
        gemm_mfma<<<nt * (nt + 1) / 2, 256, 0, stream>>>(Xhi, Xlo, sim, n, K);
    } else {
        dim3 gg(n / BN, n / BM);
        gemm_xxt<<<gg, 256, 0, stream>>>(X, sim, n, K);
    }
    row_kernel<<<n / 4, 256, 0, stream>>>(sim, row_out);
    reduce_kernel<<<1, 256, 0, stream>>>(row_out, (float*)d_out, n, k);
}

// Round 11
// 217.884 us; speedup vs baseline: 1.1448x; 1.1155x over previous
//
#include <hip/hip_runtime.h>
#include <hip/hip_bf16.h>
#include <math.h>
#include <stdint.h>

typedef short bf16x8 __attribute__((ext_vector_type(8)));
typedef float f32x4 __attribute__((ext_vector_type(4)));

#define NROW 4096
#define NEGN 4088
#define KCLS 8
#define HHALF 8372224u

// ---------------------------------------------------------------------------
// Threefry2x32 (JAX-compatible) and gumbel mapping (validated rounds 0-10)
// ---------------------------------------------------------------------------
__device__ __forceinline__ uint32_t rotl32(uint32_t v, int r) {
    return (v << r) | (v >> (32 - r));
}

__device__ __forceinline__ void threefry2x32(uint32_t k0, uint32_t k1,
                                             uint32_t& x0, uint32_t& x1) {
    uint32_t ks[3] = {k0, k1, k0 ^ k1 ^ 0x1BD11BDAu};
    const int rot[2][4] = {{13, 15, 26, 6}, {17, 29, 16, 24}};
    x0 += ks[0];
    x1 += ks[1];
#pragma unroll
    for (int i = 0; i < 5; ++i) {
#pragma unroll
        for (int r = 0; r < 4; ++r) {
            x0 += x1;
            x1 = rotl32(x1, rot[i & 1][r]);
            x1 ^= x0;
        }
        x0 += ks[(i + 1) % 3];
        x1 += ks[(i + 2) % 3] + (uint32_t)(i + 1);
    }
}

__device__ __forceinline__ float gumbel_from_bits(uint32_t bits) {
    uint32_t fb = (bits >> 9) | 0x3f800000u;
    float u = __uint_as_float(fb) - 1.0f;
    const float tiny = 1.1754943508222875e-38f;
    u = u * (1.0f - tiny) + tiny;
    u = fmaxf(tiny, u);
    return -logf(-logf(u));
}

__device__ __forceinline__ float softplus_f(float x) {
    return fmaxf(x, 0.0f) + log1pf(expf(-fabsf(x)));
}

// ---------------------------------------------------------------------------
// Cross-lane XOR exchange with cheapest available lowering (validated r7)
// ---------------------------------------------------------------------------
template <int M>
__device__ __forceinline__ int lxori(int i) {
    if constexpr (M == 1 || M == 2 || M == 3 || M == 7 || M == 8 || M == 15) {
        constexpr int ctrl = (M == 1) ? 0xB1
                           : (M == 2) ? 0x4E
                           : (M == 3) ? 0x1B
                           : (M == 7) ? 0x141
                           : (M == 8) ? 0x128
                                      : 0x140;
        return __builtin_amdgcn_update_dpp(i, i, ctrl, 0xf, 0xf, false);
    } else if constexpr (M == 4 || M == 16) {
        constexpr int off = (M == 4) ? 0x101F : 0x401F;
        return __builtin_amdgcn_ds_swizzle(i, off);
    } else if constexpr (M == 31) {
        return lxori<16>(lxori<15>(i));
    } else {
        return __shfl_xor(i, M, 64);
    }
}

template <int M>
__device__ __forceinline__ float lxorf(float x) {
    return __int_as_float(lxori<M>(__float_as_int(x)));
}

// ---------------------------------------------------------------------------
// f32 -> bf16 (hi only; lo correction dropped this round — error ~8e-5 in sim)
// ---------------------------------------------------------------------------
__global__ __launch_bounds__(256) void convert_kernel(const float* __restrict__ X,
                                                      ushort* __restrict__ Xhi,
                                                      int total4) {
    int i = blockIdx.x * 256 + threadIdx.x;
    if (i >= total4) return;
    float4 x = ((const float4*)X)[i];
    float xs[4] = {x.x, x.y, x.z, x.w};
    ushort h[4];
#pragma unroll
    for (int j = 0; j < 4; ++j) {
        __hip_bfloat16 hb = __float2bfloat16(xs[j]);
        h[j] = *(ushort*)&hb;
    }
    ((ushort4*)Xhi)[i] = make_ushort4(h[0], h[1], h[2], h[3]);
}

// ---------------------------------------------------------------------------
// MFMA GEMM, TRIANGULAR, 16x16x32, hh-only: lower-triangle tiles (i >= j);
// off-diagonal tiles mirror into the upper triangle via float4 stores.
// sim = Hi*Hi^T (bf16 rounding error ~8e-5 rms, analyzed r11 preamble).
// ---------------------------------------------------------------------------
__device__ __forceinline__ void gload_lds16(const void* g, void* l) {
    __builtin_amdgcn_global_load_lds((const __attribute__((address_space(1))) void*)g,
                                     (__attribute__((address_space(3))) void*)l, 16, 0, 0);
}

__global__ __launch_bounds__(256) void gemm_mfma(const ushort* __restrict__ Xhi,
                                                 float* __restrict__ C,
                                                 int n, int K) {
    __shared__ ushort Ah[128][32], Bh[128][32];
    const int tid = threadIdx.x;
    const int lane = tid & 63;
    const int wv = tid >> 6;
    const int wr = wv >> 1, wc = wv & 1;

    // triangular decode: block t -> (ti >= tj)
    const int t = blockIdx.x;
    int ti = (int)((sqrtf(8.0f * (float)t + 1.0f) - 1.0f) * 0.5f);
    while ((ti + 1) * (ti + 2) / 2 <= t) ++ti;
    while (ti * (ti + 1) / 2 > t) --ti;
    const int tj = t - ti * (ti + 1) / 2;
    const int bm = ti * 128, bn = tj * 128;

    f32x4 acc[4][4];
#pragma unroll
    for (int m = 0; m < 4; ++m)
#pragma unroll
        for (int q = 0; q < 4; ++q) acc[m][q] = {0.f, 0.f, 0.f, 0.f};

    const int srow = lane >> 2;
    const int scol = (lane & 3) * 8;
    const size_t rA0 = (size_t)(bm + wv * 16 + srow) * K;
    const size_t rA1 = (size_t)(bm + 64 + wv * 16 + srow) * K;
    const size_t rB0 = (size_t)(bn + wv * 16 + srow) * K;
    const size_t rB1 = (size_t)(bn + 64 + wv * 16 + srow) * K;

    for (int k0 = 0; k0 < K; k0 += 32) {
        gload_lds16(Xhi + rA0 + k0 + scol, &Ah[wv * 16][0]);
        gload_lds16(Xhi + rA1 + k0 + scol, &Ah[64 + wv * 16][0]);
        gload_lds16(Xhi + rB0 + k0 + scol, &Bh[wv * 16][0]);
        gload_lds16(Xhi + rB1 + k0 + scol, &Bh[64 + wv * 16][0]);
        __syncthreads();

        bf16x8 ah[4], bh[4];
        const int fr = lane & 15;
        const int kc = (lane >> 4) * 8;
#pragma unroll
        for (int m = 0; m < 4; ++m) {
            ah[m] = *(const bf16x8*)&Ah[wr * 64 + m * 16 + fr][kc];
            bh[m] = *(const bf16x8*)&Bh[wc * 64 + m * 16 + fr][kc];
        }
#pragma unroll
        for (int m = 0; m < 4; ++m)
#pragma unroll
            for (int q = 0; q < 4; ++q)
                acc[m][q] = __builtin_amdgcn_mfma_f32_16x16x32_bf16(ah[m], bh[q], acc[m][q], 0, 0, 0);
        __syncthreads();
    }

    // C/D layout (m89-verified): col = lane&15, row = (lane>>4)*4 + reg
    const int cr = (lane >> 4) * 4;
    const int cc = lane & 15;
    const bool offdiag = (bm != bn);
#pragma unroll
    for (int m = 0; m < 4; ++m)
#pragma unroll
        for (int q = 0; q < 4; ++q) {
            const int r0 = bm + wr * 64 + m * 16 + cr;
            const int c0 = bn + wc * 64 + q * 16 + cc;
#pragma unroll
            for (int j = 0; j < 4; ++j)
                C[(size_t)(r0 + j) * n + c0] = acc[m][q][j];
            if (offdiag) {
                float4 tv;
                tv.x = acc[m][q][0]; tv.y = acc[m][q][1];
                tv.z = acc[m][q][2]; tv.w = acc[m][q][3];
                *(float4*)&C[(size_t)c0 * n + r0] = tv;   // r0 % 4 == 0 -> aligned
            }
        }
}

// ---------------------------------------------------------------------------
// Fallback f32 vector GEMM (only if ws too small)
// ---------------------------------------------------------------------------
#define BM 128
#define BN 128
#define BKK 16

__global__ __launch_bounds__(256) void gemm_xxt(const float* __restrict__ X,
                                                float* __restrict__ C,
                                                int n, int K) {
    __shared__ float As[BKK][BM];
    __shared__ float Bs[BKK][BN];
    const int tid = threadIdx.x;
    const int tx = tid & 15;
    const int ty = tid >> 4;
    const int bm = blockIdx.y * BM;
    const int bn = blockIdx.x * BN;

    float acc[8][8];
#pragma unroll
    for (int p = 0; p < 8; ++p)
#pragma unroll
        for (int q = 0; q < 8; ++q) acc[p][q] = 0.0f;

    for (int k0 = 0; k0 < K; k0 += BKK) {
        for (int l = tid; l < BM * BKK / 4; l += 256) {
            int m = l >> 2;
            int kq = (l & 3) << 2;
            const float4 v = *(const float4*)(X + (size_t)(bm + m) * K + k0 + kq);
            As[kq + 0][m] = v.x; As[kq + 1][m] = v.y;
            As[kq + 2][m] = v.z; As[kq + 3][m] = v.w;
        }
        for (int l = tid; l < BN * BKK / 4; l += 256) {
            int m = l >> 2;
            int kq = (l & 3) << 2;
            const float4 v = *(const float4*)(X + (size_t)(bn + m) * K + k0 + kq);
            Bs[kq + 0][m] = v.x; Bs[kq + 1][m] = v.y;
            Bs[kq + 2][m] = v.z; Bs[kq + 3][m] = v.w;
        }
        __syncthreads();
#pragma unroll
        for (int kk = 0; kk < BKK; ++kk) {
            float a[8], b[8];
#pragma unroll
            for (int p = 0; p < 8; ++p) a[p] = As[kk][p * 16 + ty];
#pragma unroll
            for (int q = 0; q < 8; ++q) b[q] = Bs[kk][q * 16 + tx];
#pragma unroll
            for (int p = 0; p < 8; ++p)
#pragma unroll
                for (int q = 0; q < 8; ++q)
                    acc[p][q] = fmaf(a[p], b[q], acc[p][q]);
        }
        __syncthreads();
    }

    for (int p = 0; p < 8; ++p) {
        int r = bm + p * 16 + ty;
        for (int q = 0; q < 8; ++q) {
            C[(size_t)r * n + bn + q * 16 + tx] = acc[p][q];
        }
    }
}

// ---------------------------------------------------------------------------
// Lane-local Batcher odd-even mergesort of v[64], ascending, fully static
// ---------------------------------------------------------------------------
template <int I, int J>
__device__ __forceinline__ void ce_st(float (&v)[64]) {
    float a = v[I], b = v[J];
    v[I] = fminf(a, b);
    v[J] = fmaxf(a, b);
}

template <int I, int END, int STEP, int R>
struct CELoop {
    static __device__ __forceinline__ void run(float (&v)[64]) {
        if constexpr (I < END) {
            ce_st<I, I + R>(v);
            CELoop<I + STEP, END, STEP, R>::run(v);
        }
    }
};

template <int LO, int N, int R>
struct OEMerge {
    static __device__ __forceinline__ void run(float (&v)[64]) {
        constexpr int M = R * 2;
        if constexpr (M < N) {
            OEMerge<LO, N, M>::run(v);
            OEMerge<LO + R, N, M>::run(v);
            CELoop<LO + R, LO + N - R, M, R>::run(v);
        } else {
            ce_st<LO, LO + R>(v);
        }
    }
};

template <int LO, int N>
struct OESort {
    static __device__ __forceinline__ void run(float (&v)[64]) {
        if constexpr (N > 1) {
            OESort<LO, N / 2>::run(v);
            OESort<LO + N / 2, N / 2>::run(v);
            OEMerge<LO, N, 1>::run(v);
        }
    }
};

// ---------------------------------------------------------------------------
// Cross-lane merge with DPP/swizzle-lowered exchanges (validated r7)
// ---------------------------------------------------------------------------
template <int S>
__device__ __forceinline__ void regclean(float (&v)[64]) {
    if constexpr (S >= 1) {
#pragma unroll
        for (int r = 0; r < 64; ++r) {
            if ((r & S) == 0) {
                float a = v[r], b = v[r | S];
                v[r] = fminf(a, b);
                v[r | S] = fmaxf(a, b);
            }
        }
        regclean<(S >> 1)>(v);
    }
}

template <int T>
__device__ __forceinline__ void lanestride_clean(float (&v)[64], const int lane) {
    if constexpr (T >= 1) {
        const bool keepmin = (lane & T) == 0;
#pragma unroll
        for (int r = 0; r < 64; ++r) {
            float o = lxorf<T>(v[r]);
            float mn = fminf(v[r], o), mx = fmaxf(v[r], o);
            v[r] = keepmin ? mn : mx;
        }
        lanestride_clean<(T >> 1)>(v, lane);
    }
}

template <int G>
__device__ __forceinline__ void xmerge(float (&v)[64], const int lane) {
    const bool fh = (lane & (G >> 1)) == 0;
#pragma unroll
    for (int r = 0; r < 32; ++r) {
        float oA = lxorf<G - 1>(v[63 - r]);
        float oB = lxorf<G - 1>(v[r]);
        float a = v[r], b = v[63 - r];
        v[r]      = fh ? fminf(a, oA) : fmaxf(a, oA);
        v[63 - r] = fh ? fminf(b, oB) : fmaxf(b, oB);
    }
    lanestride_clean<(G >> 2)>(v, lane);
    regclean<32>(v);
}

// ---------------------------------------------------------------------------
// Threefry pairing (validated round 6)
// ---------------------------------------------------------------------------
template <bool LOW>
__device__ __forceinline__ void score_phase1(float (&v)[64], float (&sc)[64],
                                             float* wbuf, const int lane,
                                             const int rowlow, const float m,
                                             const float denom) {
    constexpr int RB = LOW ? 0 : 32;
#pragma unroll
    for (int rr = 0; rr < 32; ++rr) {
        const int r = RB + rr;
        uint32_t f = (uint32_t)(rowlow * NEGN + lane * 64 + r);
        uint32_t x0 = f, x1 = f + HHALF;
        threefry2x32(0u, 42u, x0, x1);
        float gown = gumbel_from_bits(LOW ? x0 : x1);
        float gpart = gumbel_from_bits(LOW ? x1 : x0);
        wbuf[lane * 33 + rr] = gpart;
        bool valid = (r < 56) || (lane < 63);
        float d = v[r] - m;
        sc[r] = valid ? (d * d) / denom + gown : -INFINITY;
    }
}

template <bool LOW>
__device__ __forceinline__ void score_phase2(float (&v)[64], float (&sc)[64],
                                             const float* rbuf, const int lane,
                                             const float m, const float denom) {
    constexpr int RB = LOW ? 32 : 0;
#pragma unroll
    for (int rr = 0; rr < 32; ++rr) {
        const int r = RB + rr;
        float g = rbuf[lane * 33 + rr];
        bool valid = (r < 56) || (lane < 63);
        float d = v[r] - m;
        sc[r] = valid ? (d * d) / denom + g : -INFINITY;
    }
}

// ---------------------------------------------------------------------------
// Per-row kernel (validated round 7, unchanged)
// ---------------------------------------------------------------------------
__global__ __launch_bounds__(256, 1) void row_kernel(const float* __restrict__ sim,
                                                     float* __restrict__ row_out) {
    __shared__ float bufL[2][64 * 33];
    __shared__ float bufH[2][64 * 33];

    const int lane = threadIdx.x & 63;
    const int wv = threadIdx.x >> 6;
    const bool low = (wv < 2);
    const int p = wv & 1;
    const int rowlow = blockIdx.x * 2 + p;
    const int row = low ? rowlow : rowlow + 2048;
    const float* simrow = sim + (size_t)row * NROW;
    const int base = row & ~(KCLS - 1);
    const int posrq = base >> 8;

    float v[64];
    float nsum = 0.0f, psum = 0.0f, plos = 0.0f, pmax = -INFINITY;

#pragma unroll
    for (int rq = 0; rq < 16; ++rq) {
        const float4 w4 = *(const float4*)(simrow + rq * 256 + lane * 4);
        float e[4] = {w4.x, w4.y, w4.z, w4.w};
        if (rq == posrq) {
#pragma unroll
            for (int c = 0; c < 4; ++c) {
                int col = rq * 256 + lane * 4 + c;
                float val = e[c];
                bool ispos = (col >= base) && (col < base + KCLS);
                if (ispos) {
                    if (col != row) {
                        psum += val;
                        pmax = fmaxf(pmax, val);
                        plos += softplus_f(-2.0f * (val - 0.5f));
                    }
                    v[rq * 4 + c] = INFINITY;
                } else {
                    nsum += val;
                    v[rq * 4 + c] = val;
                }
            }
        } else {
#pragma unroll
            for (int c = 0; c < 4; ++c) {
                nsum += e[c];
                v[rq * 4 + c] = e[c];
            }
        }
    }

#define BSTEP(M)                                   \
    nsum += lxorf<M>(nsum);                        \
    psum += lxorf<M>(psum);                        \
    plos += lxorf<M>(plos);                        \
    pmax = fmaxf(pmax, lxorf<M>(pmax));
    BSTEP(1) BSTEP(2) BSTEP(4) BSTEP(8) BSTEP(16) BSTEP(32)
#undef BSTEP
    const float m = nsum / (float)NEGN;

    OESort<0, 64>::run(v);
    xmerge<2>(v, lane);
    xmerge<4>(v, lane);
    xmerge<8>(v, lane);
    xmerge<16>(v, lane);
    xmerge<32>(v, lane);
    xmerge<64>(v, lane);

    float vs = 0.0f;
#pragma unroll
    for (int r = 0; r < 64; ++r) {
        bool valid = (r < 56) || (lane < 63);
        float d = v[r] - m;
        vs += valid ? d * d : 0.0f;
    }
    vs += lxorf<1>(vs); vs += lxorf<2>(vs); vs += lxorf<4>(vs);
    vs += lxorf<8>(vs); vs += lxorf<16>(vs); vs += lxorf<32>(vs);
    const float var = vs / (float)NEGN;
    const float sd = sqrtf(var);
    const float denom = 2.0f * sd * sd;

    float sc[64];
    if (low) score_phase1<true>(v, sc, &bufL[p][0], lane, rowlow, m, denom);
    else     score_phase1<false>(v, sc, &bufH[p][0], lane, rowlow, m, denom);
    __syncthreads();
    if (low) score_phase2<true>(v, sc, &bufH[p][0], lane, m, denom);
    else     score_phase2<false>(v, sc, &bufL[p][0], lane, m, denom);

    float nl = 0.0f, neg_last = 0.0f;
    const int lb = lane * 64;
    for (int t = 0; t < 7; ++t) {
        float bs4[4], bv4[4];
        int bi4[4];
#pragma unroll
        for (int g = 0; g < 4; ++g) { bs4[g] = -INFINITY; bv4[g] = 0.f; bi4[g] = 0x7fffffff; }
#pragma unroll
        for (int j = 0; j < 16; ++j) {
#pragma unroll
            for (int g = 0; g < 4; ++g) {
                const int r = g * 16 + j;
                if (sc[r] > bs4[g]) { bs4[g] = sc[r]; bv4[g] = v[r]; bi4[g] = lb + r; }
            }
        }
        float bs = bs4[0], bv = bv4[0];
        int bi = bi4[0];
#pragma unroll
        for (int g = 1; g < 4; ++g) {
            if (bs4[g] > bs) { bs = bs4[g]; bv = bv4[g]; bi = bi4[g]; }
        }
#define TSTEP(M)                                                          \
        {                                                                 \
            float os = lxorf<M>(bs);                                      \
            float ov = lxorf<M>(bv);                                      \
            int oi = lxori<M>(bi);                                        \
            if (os > bs || (os == bs && oi < bi)) { bs = os; bv = ov; bi = oi; } \
        }
        TSTEP(1) TSTEP(2) TSTEP(4) TSTEP(8) TSTEP(16) TSTEP(32)
#undef TSTEP
        nl += softplus_f(50.0f * (bv - 0.5f));
        if (t == 6) neg_last = bv;
        const int bl = bi - lb;
#pragma unroll
        for (int r = 0; r < 64; ++r)
            if (r == bl) sc[r] = -INFINITY;
    }

    if (lane == 0) {
        float pos_loss = plos / (float)(KCLS - 1);
        float neg_loss = 0.04f * (nl / (float)(KCLS - 1));
        row_out[row * 4 + 0] = pos_loss + neg_loss;
        row_out[row * 4 + 1] = (pmax > neg_last + 0.05f) ? 1.0f : 0.0f;
        row_out[row * 4 + 2] = psum;
        row_out[row * 4 + 3] = nsum;
    }
}

// ---------------------------------------------------------------------------
// Deterministic final reduction (single block, f64 accumulation)
// ---------------------------------------------------------------------------
__global__ __launch_bounds__(256) void reduce_kernel(const float* __restrict__ row_out,
                                                     float* __restrict__ out,
                                                     int n, int k) {
    __shared__ double sh[4][256];
    const int tid = threadIdx.x;
    double a = 0.0, b = 0.0, c = 0.0, d = 0.0;
    for (int i = tid; i < n; i += 256) {
        a += (double)row_out[i * 4 + 0];
        b += (double)row_out[i * 4 + 1];
        c += (double)row_out[i * 4 + 2];
        d += (double)row_out[i * 4 + 3];
    }
    sh[0][tid] = a; sh[1][tid] = b; sh[2][tid] = c; sh[3][tid] = d;
    __syncthreads();
    for (int off = 128; off; off >>= 1) {
        if (tid < off) {
            sh[0][tid] += sh[0][tid + off];
            sh[1][tid] += sh[1][tid + off];
            sh[2][tid] += sh[2][tid + off];
            sh[3][tid] += sh[3][tid + off];
        }
        __syncthreads();
    }
    if (tid == 0) {
        out[0] = (float)(sh[0][0] / (double)n);
        out[1] = (float)(sh[1][0] / (double)n);
        out[2] = (float)(sh[2][0] / ((double)n * (double)(k - 1)));
        out[3] = (float)(sh[3][0] / ((double)n * (double)(n - k)));
    }
}

// ---------------------------------------------------------------------------
extern "C" void kernel_launch(void* const* d_in, const int* in_sizes, int n_in,
                              void* d_out, int out_size, void* d_ws, size_t ws_size,
                              hipStream_t stream) {
    const float* X = (const float*)d_in[0];
    const int n = in_sizes[1];            // 4096
    const int K = in_sizes[0] / n;        // 1024
    const int k = 8;

    const size_t simB = (size_t)n * n * sizeof(float);
    const size_t rowB = (size_t)n * 4 * sizeof(float);
    float* sim = (float*)d_ws;
    float* row_out = (float*)((char*)d_ws + simB);
    ushort* Xhi = (ushort*)((char*)d_ws + simB + rowB);
    const size_t need = simB + rowB + (size_t)n * K * sizeof(ushort);

    if (ws_size >= need) {
        const int total4 = n * K / 4;
        convert_kernel<<<(total4 + 255) / 256, 256, 0, stream>>>(X, Xhi, total4);
        const int nt = n / 128;
        gemm_mfma<<<nt * (nt + 1) / 2, 256, 0, stream>>>(Xhi, sim, n, K);
    } else {
        dim3 gg(n / BN, n / BM);
        gemm_xxt<<<gg, 256, 0, stream>>>(X, sim, n, K);
    }
    row_kernel<<<n / 4, 256, 0, stream>>>(sim, row_out);
    reduce_kernel<<<1, 256, 0, stream>>>(row_out, (float*)d_out, n, k);
}